// Round 18
// baseline (173.226 us; speedup 1.0000x reference)
//
#include <hip/hip_runtime.h>
#include <cstddef>

#define HID 128
#define NEG_SLOPE 0.2f
#define LN_EPS 1e-5f

typedef float floatx4 __attribute__((ext_vector_type(4)));
typedef short bf16x8 __attribute__((ext_vector_type(8)));
typedef int intx4 __attribute__((ext_vector_type(4)));
typedef unsigned short u16;
typedef unsigned int u32;

#define MFMA(a, b, c) __builtin_amdgcn_mfma_f32_16x16x32_bf16((a), (b), (c), 0, 0, 0)

__device__ __forceinline__ u16 f2bf(float f) {
  union { float f; unsigned u; } v; v.f = f;
  unsigned r = v.u + 0x7FFF + ((v.u >> 16) & 1);
  return (u16)(r >> 16);
}
__device__ __forceinline__ float bf2f(u16 s) {
  union { unsigned u; float f; } v; v.u = ((unsigned)s) << 16;
  return v.f;
}

// ---------------------------------------------------------------------------
// K_prep: fused { gat_w transpose->bf16 | cnt zeroing }
//   blocks [0, 128)        : Wg16[j][k] = bf16(gat_w[k][j])
//   blocks [128, 128+NZB)  : cnt[i] = 0
// ---------------------------------------------------------------------------
__global__ void K_prep(const float* __restrict__ W, u16* __restrict__ Wg16,
                       int* __restrict__ cnt, int N) {
  const int b = blockIdx.x;
  if (b < HID) {
    const int j = b, k = threadIdx.x;
    Wg16[j*HID + k] = f2bf(W[k*HID + j]);
  } else {
    int i = (b - HID) * 128 + threadIdx.x;
    if (i < N) cnt[i] = 0;
  }
}

// ---------------------------------------------------------------------------
// K_front: fused { xp_mfma | build_G | hist_rank }; all blocks co-resident
// (4 blocks/CU * 256 CU = 1024 at 34.8KB LDS/block) => full overlap.
// ---------------------------------------------------------------------------
__global__ __launch_bounds__(256) void K_front(
    const float* __restrict__ x, const u16* __restrict__ Wg16,
    const float* __restrict__ att_src, const float* __restrict__ att_dst,
    u16* __restrict__ xp, float* __restrict__ a_src, float* __restrict__ a_dst,
    int nrows, int ntXP, int NHc,
    const float* __restrict__ pc_w, float* __restrict__ G,
    const int* __restrict__ ei, int E, int N,
    int* __restrict__ cnt, int* __restrict__ rank)
{
  __shared__ u16 Wt[128 * 136];
  const int b = blockIdx.x;
  const int tid = threadIdx.x;

  if (b < ntXP) {
    // ---------------- xp_mfma ----------------
    {
      #pragma unroll
      for (int i = 0; i < 8; ++i) {
        int idx = tid + i*256;
        bf16x8 w = *(const bf16x8*)(Wg16 + (size_t)idx*8);
        *(bf16x8*)&Wt[(idx >> 4)*136 + (idx & 15)*8] = w;
      }
    }
    __syncthreads();
    const int lane = tid & 63, wave = tid >> 6;
    const int lr = lane & 15, lg = lane >> 4;
    const int rowbase = b*128 + wave*32;

    bf16x8 a[2][4];
    #pragma unroll
    for (int rf = 0; rf < 2; ++rf) {
      int row = min(rowbase + rf*16 + lr, nrows-1);
      const float* p = x + (size_t)row*HID + lg*8;
      #pragma unroll
      for (int kc = 0; kc < 4; ++kc) {
        float4 q0 = *(const float4*)(p + kc*32);
        float4 q1 = *(const float4*)(p + kc*32 + 4);
        union { bf16x8 v; u16 s[8]; } u;
        u.s[0]=f2bf(q0.x); u.s[1]=f2bf(q0.y); u.s[2]=f2bf(q0.z); u.s[3]=f2bf(q0.w);
        u.s[4]=f2bf(q1.x); u.s[5]=f2bf(q1.y); u.s[6]=f2bf(q1.z); u.s[7]=f2bf(q1.w);
        a[rf][kc] = u.v;
      }
    }
    floatx4 acc[2][8];
    #pragma unroll
    for (int rf = 0; rf < 2; ++rf)
      #pragma unroll
      for (int cf = 0; cf < 8; ++cf) acc[rf][cf] = (floatx4){0,0,0,0};
    #pragma unroll
    for (int kc = 0; kc < 4; ++kc)
      #pragma unroll
      for (int cf = 0; cf < 8; ++cf) {
        bf16x8 bb = *(const bf16x8*)&Wt[(cf*16+lr)*136 + kc*32 + lg*8];
        acc[0][cf] = MFMA(a[0][kc], bb, acc[0][cf]);
        acc[1][cf] = MFMA(a[1][kc], bb, acc[1][cf]);
      }
    float asv[8], adv[8];
    #pragma unroll
    for (int cf = 0; cf < 8; ++cf) {
      asv[cf] = att_src[cf*16 + lr];
      adv[cf] = att_dst[cf*16 + lr];
    }
    #pragma unroll
    for (int rf = 0; rf < 2; ++rf) {
      #pragma unroll
      for (int j = 0; j < 4; ++j) {
        int row = rowbase + rf*16 + lg*4 + j;
        if (row < nrows) {
          #pragma unroll
          for (int cf = 0; cf < 8; ++cf)
            xp[(size_t)row*HID + cf*16 + lr] = f2bf(acc[rf][cf][j]);
        }
        #pragma unroll
        for (int h = 0; h < 4; ++h) {
          float ps = acc[rf][2*h][j]*asv[2*h] + acc[rf][2*h+1][j]*asv[2*h+1];
          float pd = acc[rf][2*h][j]*adv[2*h] + acc[rf][2*h+1][j]*adv[2*h+1];
          #pragma unroll
          for (int m = 1; m < 16; m <<= 1) { ps += __shfl_xor(ps, m); pd += __shfl_xor(pd, m); }
          if (lr == 0 && row < nrows) {
            a_src[(size_t)row*4 + h] = ps;
            a_dst[(size_t)row*4 + h] = pd;
          }
        }
      }
    }
  } else if (b < ntXP + 64) {
    // ---------------- build_G (2 rows/block) ----------------
    int i = (b - ntXP)*2 + (tid >> 7);
    int j = tid & 127;
    float s = 0.f;
    for (int k = 0; k < HID; ++k) s = fmaf(pc_w[k*HID + i], pc_w[k*HID + j], s);
    G[i*HID + j] = s;
  } else {
    // ---------------- hist_rank (grid-stride) ----------------
    const int vb = b - (ntXP + 64);
    const int E4 = E >> 2;
    const intx4* dst4 = (const intx4*)(ei + (size_t)E);
    intx4* rank4 = (intx4*)rank;
    const int stride = NHc * 256;
    for (int i4 = vb*256 + tid; i4 < E4; i4 += stride) {
      intx4 d4 = __builtin_nontemporal_load(&dst4[i4]);
      intx4 r;
      r.x = ((unsigned)d4.x < (unsigned)N) ? atomicAdd(&cnt[d4.x], 1) : 0;
      r.y = ((unsigned)d4.y < (unsigned)N) ? atomicAdd(&cnt[d4.y], 1) : 0;
      r.z = ((unsigned)d4.z < (unsigned)N) ? atomicAdd(&cnt[d4.z], 1) : 0;
      r.w = ((unsigned)d4.w < (unsigned)N) ? atomicAdd(&cnt[d4.w], 1) : 0;
      rank4[i4] = r;
    }
    if (vb == 0 && tid < (E & 3)) {
      int idx = (E4 << 2) + tid;
      int d = ei[(size_t)E + idx];
      rank[idx] = ((unsigned)d < (unsigned)N) ? atomicAdd(&cnt[d], 1) : 0;
    }
  }
}

// ---------------------------------------------------------------------------
// K_scan: fused { scan_local | mat_sq }  (1024 threads)
// ---------------------------------------------------------------------------
__global__ __launch_bounds__(1024) void K_scan(
    const int* __restrict__ cnt, int* __restrict__ row_ptr,
    int* __restrict__ blk_tot, int N, int NB,
    const float* __restrict__ G, float* __restrict__ Hm)
{
  __shared__ int sd[1024];
  const int b = blockIdx.x;
  const int tid = threadIdx.x;
  if (b < NB) {
    int i = b * 1024 + tid;
    int v = (i < N) ? cnt[i] : 0;
    sd[tid] = v;
    __syncthreads();
    for (int off = 1; off < 1024; off <<= 1) {
      int t = (tid >= off) ? sd[tid - off] : 0;
      __syncthreads();
      sd[tid] += t;
      __syncthreads();
    }
    if (i < N) row_ptr[i] = sd[tid] - v;
    if (tid == 1023) blk_tot[b] = sd[1023];
  } else {
    int i = (b - NB)*8 + (tid >> 7);
    int j = tid & 127;
    float s = 0.f;
    for (int k = 0; k < HID; ++k) s = fmaf(G[i*HID + k], G[k*HID + j], s);
    Hm[i*HID + j] = s;
  }
}

// ---------------------------------------------------------------------------
// K_apply: fused { scan_apply | power_iter }  (256 threads)
// ---------------------------------------------------------------------------
__global__ __launch_bounds__(256) void K_apply(
    int* __restrict__ row_ptr, const int* __restrict__ blk_tot, int N, int NB,
    const float* __restrict__ H, float* __restrict__ out_inv_sigma)
{
  __shared__ __align__(16) float Hl[128 * 132];
  __shared__ __align__(16) float v[132];
  __shared__ float ybuf[256];
  __shared__ float red[8];
  __shared__ int s_off;
  const int b = blockIdx.x;
  const int tid = threadIdx.x;

  if (b < NB) {
    if (tid < 64) {
      int carry = 0;
      for (int base = 0; base < NB; base += 64) {
        int i = base + tid;
        int vv = (i < NB) ? blk_tot[i] : 0;
        int inc = vv;
        #pragma unroll
        for (int m = 1; m < 64; m <<= 1) {
          int t = __shfl_up(inc, m);
          if (tid >= m) inc += t;
        }
        if (i == b) s_off = carry + inc - vv;
        int tot = __shfl(inc, 63);
        carry += tot;
      }
      if (b == 0 && tid == 0) row_ptr[N] = carry;
    }
    __syncthreads();
    int lim = min(N, (b + 1) * 1024);
    for (int i = b * 1024 + tid; i < lim; i += 256) row_ptr[i] += s_off;
  } else {
    {
      const float4* H4 = (const float4*)H;
      float4* Hl4 = (float4*)Hl;
      #pragma unroll
      for (int idx = tid; idx < 128*32; idx += 256) {
        int r = idx >> 5, c = idx & 31;
        Hl4[r*33 + c] = H4[idx];
      }
    }
    if (tid < 128) v[tid] = 1.0f + 0.001f * (float)tid;
    __syncthreads();
    const int j = tid & 127, half = tid >> 7;
    float rho = 0.f;
    for (int it = 0; it < 20; ++it) {
      const float4* hrow = (const float4*)(Hl + j*132 + half*64);
      const float4* vrow = (const float4*)(v) + half*16;
      float y = 0.f;
      #pragma unroll
      for (int q = 0; q < 16; ++q) {
        float4 hq = hrow[q];
        float4 vq = vrow[q];
        y += hq.x*vq.x + hq.y*vq.y + hq.z*vq.z + hq.w*vq.w;
      }
      ybuf[tid] = y;
      __syncthreads();
      float yj = 0.f, vy = 0.f, yy = 0.f;
      if (tid < 128) {
        yj = ybuf[tid] + ybuf[tid + 128];
        vy = v[tid] * yj;
        yy = yj * yj;
      }
      #pragma unroll
      for (int m = 1; m < 64; m <<= 1) { vy += __shfl_xor(vy, m); yy += __shfl_xor(yy, m); }
      if ((tid & 63) == 0) { red[tid>>6] = vy; red[4 + (tid>>6)] = yy; }
      __syncthreads();
      float vyT = red[0] + red[1] + red[2] + red[3];
      float yyT = red[4] + red[5] + red[6] + red[7];
      rho = vyT;
      if (tid < 128) v[tid] = yj * rsqrtf(yyT);
      __syncthreads();
    }
    if (tid == 0) out_inv_sigma[0] = 1.0f / sqrtf(sqrtf(rho));
  }
}

// ---------------------------------------------------------------------------
// K_fill: fused { fill_rank | prep_all }
// ---------------------------------------------------------------------------
__global__ __launch_bounds__(256) void K_fill(
    const int* __restrict__ ei, int E, int N,
    const int* __restrict__ row_ptr, const int* __restrict__ rank,
    int* __restrict__ csr_src,
    const float* __restrict__ pc_w, const float* __restrict__ sigma_inv,
    const float* __restrict__ mgf_w, const float* __restrict__ mgf_b,
    const float* __restrict__ sym_w, const float* __restrict__ sym_b,
    const float* __restrict__ out_w,
    u16* __restrict__ W1t, u16* __restrict__ W2t,
    u16* __restrict__ Wot, float* __restrict__ bias2)
{
  const int b = blockIdx.x;
  const int tid = threadIdx.x;
  if (b < 1024) {
    const int E4 = E >> 2;
    const intx4* src4v = (const intx4*)ei;
    const intx4* dst4v = (const intx4*)(ei + (size_t)E);
    const intx4* rank4 = (const intx4*)rank;
    const int stride = 1024 * 256;
    for (int i4 = b*256 + tid; i4 < E4; i4 += stride) {
      intx4 d4 = __builtin_nontemporal_load(&dst4v[i4]);
      intx4 s4 = __builtin_nontemporal_load(&src4v[i4]);
      intx4 r4 = __builtin_nontemporal_load(&rank4[i4]);
      if ((unsigned)d4.x < (unsigned)N && (unsigned)s4.x < (unsigned)N)
        csr_src[row_ptr[d4.x] + r4.x] = s4.x;
      if ((unsigned)d4.y < (unsigned)N && (unsigned)s4.y < (unsigned)N)
        csr_src[row_ptr[d4.y] + r4.y] = s4.y;
      if ((unsigned)d4.z < (unsigned)N && (unsigned)s4.z < (unsigned)N)
        csr_src[row_ptr[d4.z] + r4.z] = s4.z;
      if ((unsigned)d4.w < (unsigned)N && (unsigned)s4.w < (unsigned)N)
        csr_src[row_ptr[d4.w] + r4.w] = s4.w;
    }
    if (b == 0 && tid < (E & 3)) {
      int idx = ((E >> 2) << 2) + tid;
      int d = ei[(size_t)E + idx];
      int s = ei[idx];
      if ((unsigned)d < (unsigned)N && (unsigned)s < (unsigned)N)
        csr_src[row_ptr[d] + rank[idx]] = s;
    }
  } else if (tid < 128) {
    const int bb = b - 1024;
    const int j = tid;
    if (bb < HID) {
      float s = 0.f;
      for (int m = 0; m < HID; ++m) s = fmaf(mgf_w[bb*HID + m], sym_w[m*HID + j], s);
      W2t[j*HID + bb] = f2bf(s);
    } else if (bb == HID) {
      float s = sym_b[j];
      for (int m = 0; m < HID; ++m) s = fmaf(mgf_b[m], sym_w[m*HID + j], s);
      bias2[j] = s;
    } else if (bb == HID + 1) {
      float sc = sigma_inv[0];
      for (int k = 0; k < HID; ++k) W1t[j*HID + k] = f2bf(pc_w[k*HID + j] * sc);
    } else {
      int p = bb - (HID + 2);
      for (int k = 0; k < HID; ++k)
        Wot[p*HID*HID + j*HID + k] = f2bf(out_w[(size_t)(p*HID + k)*HID + j]);
    }
  }
}

// ---------------------------------------------------------------------------
// GAT aggregation: 256-thread blocks, 4 dsts/block (1 wave each) -> 32 waves/CU
// TLP for latency hiding (64-thread blocks were capped by WG slots).
// ---------------------------------------------------------------------------
__global__ __launch_bounds__(256) void gat_aggregate(
    const u16* __restrict__ xp, const float* __restrict__ a_src,
    const float* __restrict__ a_dst, const int* __restrict__ row_ptr,
    const int* __restrict__ csr_src, const float* __restrict__ gat_b,
    u16* __restrict__ h_gat, int N)
{
  const int wave = threadIdx.x >> 6;
  const int d = blockIdx.x * 4 + wave;
  if (d >= N) return;
  const int lane = threadIdx.x & 63;
  const int hh = lane >> 4;
  const int c0 = lane * 2;
  const int beg = row_ptr[d], end = row_ptr[d+1];

  const float ad = a_dst[(size_t)d*4 + hh];
  float e0 = a_src[(size_t)d*4 + hh] + ad;
  e0 = (e0 > 0.f) ? e0 : NEG_SLOPE * e0;
  float w0 = __expf(e0);
  u32 xv = *(const u32*)(xp + (size_t)d*HID + c0);
  float acc0 = w0 * bf2f((u16)(xv & 0xFFFF));
  float acc1 = w0 * bf2f((u16)(xv >> 16));
  float den = w0;

  int i = beg;
  for (; i + 4 <= end; i += 4) {
    int s0 = csr_src[i+0], s1 = csr_src[i+1], s2 = csr_src[i+2], s3 = csr_src[i+3];
    float eA = a_src[(size_t)s0*4 + hh] + ad;
    float eB = a_src[(size_t)s1*4 + hh] + ad;
    float eC = a_src[(size_t)s2*4 + hh] + ad;
    float eD = a_src[(size_t)s3*4 + hh] + ad;
    eA = (eA > 0.f) ? eA : NEG_SLOPE * eA;
    eB = (eB > 0.f) ? eB : NEG_SLOPE * eB;
    eC = (eC > 0.f) ? eC : NEG_SLOPE * eC;
    eD = (eD > 0.f) ? eD : NEG_SLOPE * eD;
    float wA = __expf(eA), wB = __expf(eB), wC = __expf(eC), wD = __expf(eD);
    u32 xA = *(const u32*)(xp + (size_t)s0*HID + c0);
    u32 xB = *(const u32*)(xp + (size_t)s1*HID + c0);
    u32 xC = *(const u32*)(xp + (size_t)s2*HID + c0);
    u32 xD = *(const u32*)(xp + (size_t)s3*HID + c0);
    acc0 = fmaf(wA, bf2f((u16)(xA & 0xFFFF)), acc0);
    acc1 = fmaf(wA, bf2f((u16)(xA >> 16)),    acc1);
    acc0 = fmaf(wB, bf2f((u16)(xB & 0xFFFF)), acc0);
    acc1 = fmaf(wB, bf2f((u16)(xB >> 16)),    acc1);
    acc0 = fmaf(wC, bf2f((u16)(xC & 0xFFFF)), acc0);
    acc1 = fmaf(wC, bf2f((u16)(xC >> 16)),    acc1);
    acc0 = fmaf(wD, bf2f((u16)(xD & 0xFFFF)), acc0);
    acc1 = fmaf(wD, bf2f((u16)(xD >> 16)),    acc1);
    den += (wA + wB) + (wC + wD);
  }
  for (; i < end; ++i) {
    int s = csr_src[i];
    float e = a_src[(size_t)s*4 + hh] + ad;
    e = (e > 0.f) ? e : NEG_SLOPE * e;
    float w = __expf(e);
    u32 xw = *(const u32*)(xp + (size_t)s*HID + c0);
    acc0 = fmaf(w, bf2f((u16)(xw & 0xFFFF)), acc0);
    acc1 = fmaf(w, bf2f((u16)(xw >> 16)),    acc1);
    den += w;
  }
  float inv = 1.0f / (den + 1e-16f);
  float o0 = acc0 * inv + gat_b[c0];
  float o1 = acc1 * inv + gat_b[c0 + 1];
  u32 pack = (u32)f2bf(o0) | ((u32)f2bf(o1) << 16);
  *(u32*)(h_gat + (size_t)d*HID + c0) = pack;
}

// ---------------------------------------------------------------------------
// tail_fused: 256 threads, 64 rows/block. 5 GEMM passes over ONE LDS weight
// buffer (restaged with barriers, issue-early/write-late). T is wave-local.
// ---------------------------------------------------------------------------
__global__ __launch_bounds__(256) void tail_fused(
    const u16* __restrict__ A,
    const u16* __restrict__ W1t, const float* __restrict__ b1,
    const float* __restrict__ g1, const float* __restrict__ bb1,
    const u16* __restrict__ W2t, const float* __restrict__ b2,
    const float* __restrict__ g2, const float* __restrict__ bb2,
    const u16* __restrict__ Wot,
    const float* __restrict__ out_b,
    const float* __restrict__ norm_g, const float* __restrict__ norm_b,
    float* __restrict__ Cout, int nrows)
{
  __shared__ u16 Wbuf[128 * 136];
  __shared__ u16 T[64 * 136];
  const int tid = threadIdx.x;
  const int lane = tid & 63, wave = tid >> 6;
  const int lr = lane & 15, lg = lane >> 4;
  const int rowbase = blockIdx.x * 64;

  int arow = min(rowbase + wave*16 + lr, nrows-1);
  const u16* ap = A + (size_t)arow*HID + lg*8;
  bf16x8 a0 = *(const bf16x8*)(ap);
  bf16x8 a1 = *(const bf16x8*)(ap + 32);
  bf16x8 a2 = *(const bf16x8*)(ap + 64);
  bf16x8 a3 = *(const bf16x8*)(ap + 96);

  bf16x8 st[8];
  auto loadW = [&](const u16* Wsrc) {
    #pragma unroll
    for (int i = 0; i < 8; ++i)
      st[i] = *(const bf16x8*)(Wsrc + (size_t)(tid + i*256) * 8);
  };
  auto writeW = [&]() {
    #pragma unroll
    for (int i = 0; i < 8; ++i) {
      int c = tid + i*256;
      *(bf16x8*)&Wbuf[(c >> 4)*136 + (c & 15)*8] = st[i];
    }
  };
  auto gemmW = [&](floatx4* acc, bf16x8 x0, bf16x8 x1, bf16x8 x2, bf16x8 x3) {
    #pragma unroll
    for (int cf = 0; cf < 8; ++cf) {
      const u16* wb = &Wbuf[(cf*16+lr)*136 + lg*8];
      acc[cf] = MFMA(x0, *(const bf16x8*)(wb),       acc[cf]);
      acc[cf] = MFMA(x1, *(const bf16x8*)(wb + 32),  acc[cf]);
      acc[cf] = MFMA(x2, *(const bf16x8*)(wb + 64),  acc[cf]);
      acc[cf] = MFMA(x3, *(const bf16x8*)(wb + 96),  acc[cf]);
    }
  };
  auto epiT = [&](floatx4* acc, const float* bias, const float* lng, const float* lnb) {
    #pragma unroll
    for (int j = 0; j < 4; ++j) {
      float vv[8]; float s1 = 0.f, s2 = 0.f;
      #pragma unroll
      for (int cf = 0; cf < 8; ++cf) {
        vv[cf] = acc[cf][j] + bias[cf*16 + lr];
        s1 += vv[cf]; s2 += vv[cf]*vv[cf];
      }
      #pragma unroll
      for (int m = 1; m < 16; m <<= 1) { s1 += __shfl_xor(s1, m); s2 += __shfl_xor(s2, m); }
      float mean = s1 * (1.0f/128.0f);
      float var  = s2 * (1.0f/128.0f) - mean*mean;
      float rstd = rsqrtf(var + LN_EPS);
      int lrow = wave*16 + lg*4 + j;
      #pragma unroll
      for (int cf = 0; cf < 8; ++cf) {
        float o = fmaxf((vv[cf]-mean)*rstd*lng[cf*16+lr] + lnb[cf*16+lr], 0.f);
        T[lrow*136 + cf*16 + lr] = f2bf(o);
      }
    }
  };

  floatx4 accO[8];
  #pragma unroll
  for (int cf = 0; cf < 8; ++cf) accO[cf] = (floatx4){0,0,0,0};

  loadW(W1t);
  writeW(); __syncthreads();
  loadW(Wot + (size_t)1*HID*HID);
  {
    floatx4 accT[8];
    #pragma unroll
    for (int cf = 0; cf < 8; ++cf) accT[cf] = (floatx4){0,0,0,0};
    gemmW(accT, a0, a1, a2, a3);
    epiT(accT, b1, g1, bb1);
  }
  __syncthreads();
  writeW(); __syncthreads();
  loadW(W2t);
  {
    const u16* tp = &T[(wave*16 + lr)*136 + lg*8];
    bf16x8 t0 = *(const bf16x8*)(tp);
    bf16x8 t1 = *(const bf16x8*)(tp + 32);
    bf16x8 t2 = *(const bf16x8*)(tp + 64);
    bf16x8 t3 = *(const bf16x8*)(tp + 96);
    gemmW(accO, t0, t1, t2, t3);
  }
  __syncthreads();
  writeW(); __syncthreads();
  loadW(Wot + (size_t)2*HID*HID);
  {
    floatx4 accT[8];
    #pragma unroll
    for (int cf = 0; cf < 8; ++cf) accT[cf] = (floatx4){0,0,0,0};
    gemmW(accT, a0, a1, a2, a3);
    epiT(accT, b2, g2, bb2);
  }
  __syncthreads();
  writeW(); __syncthreads();
  loadW(Wot);
  {
    const u16* tp = &T[(wave*16 + lr)*136 + lg*8];
    bf16x8 t0 = *(const bf16x8*)(tp);
    bf16x8 t1 = *(const bf16x8*)(tp + 32);
    bf16x8 t2 = *(const bf16x8*)(tp + 64);
    bf16x8 t3 = *(const bf16x8*)(tp + 96);
    gemmW(accO, t0, t1, t2, t3);
  }
  __syncthreads();
  writeW(); __syncthreads();
  gemmW(accO, a0, a1, a2, a3);

  #pragma unroll
  for (int j = 0; j < 4; ++j) {
    float vv[8]; float s1 = 0.f, s2 = 0.f;
    #pragma unroll
    for (int cf = 0; cf < 8; ++cf) {
      vv[cf] = accO[cf][j] + out_b[cf*16 + lr];
      s1 += vv[cf]; s2 += vv[cf]*vv[cf];
    }
    #pragma unroll
    for (int m = 1; m < 16; m <<= 1) { s1 += __shfl_xor(s1, m); s2 += __shfl_xor(s2, m); }
    float mean = s1 * (1.0f/128.0f);
    float var  = s2 * (1.0f/128.0f) - mean*mean;
    float rstd = rsqrtf(var + LN_EPS);
    int row = rowbase + wave*16 + lg*4 + j;
    if (row < nrows) {
      #pragma unroll
      for (int cf = 0; cf < 8; ++cf)
        Cout[(size_t)row*HID + cf*16 + lr] = (vv[cf]-mean)*rstd*norm_g[cf*16+lr] + norm_b[cf*16+lr];
    }
  }
}

// ---------------------------------------------------------------------------
// launch
// ---------------------------------------------------------------------------
extern "C" void kernel_launch(void* const* d_in, const int* in_sizes, int n_in,
                              void* d_out, int out_size, void* d_ws, size_t ws_size,
                              hipStream_t stream) {
  const float* x       = (const float*)d_in[0];
  const float* gat_w   = (const float*)d_in[2];
  const float* att_src = (const float*)d_in[3];
  const float* att_dst = (const float*)d_in[4];
  const float* gat_b   = (const float*)d_in[5];
  const float* pc_w    = (const float*)d_in[6];
  const float* pc_b    = (const float*)d_in[7];
  const float* pc_g    = (const float*)d_in[8];
  const float* pc_bb   = (const float*)d_in[9];
  const float* mgf_w   = (const float*)d_in[10];
  const float* mgf_b   = (const float*)d_in[11];
  const float* sym_w   = (const float*)d_in[12];
  const float* sym_b   = (const float*)d_in[13];
  const float* sym_g   = (const float*)d_in[14];
  const float* sym_bb  = (const float*)d_in[15];
  const float* out_w   = (const float*)d_in[16];
  const float* out_b   = (const float*)d_in[17];
  const float* norm_g  = (const float*)d_in[18];
  const float* norm_b  = (const float*)d_in[19];
  const int*   ei      = (const int*)d_in[20];

  const int N = in_sizes[0] / HID;
  const int E = in_sizes[1];
  const int NB = (N + 1023) / 1024;
  const int NZB = (N + 127) / 128;

  char* ws = (char*)d_ws;
  size_t off = 0;
  auto alloc = [&](size_t bytes) -> void* {
    void* p = ws + off;
    off += (bytes + 255) & ~(size_t)255;
    return p;
  };
  u16*   xp       = (u16*)alloc((size_t)N * HID * 2);
  u16*   h_gat    = (u16*)alloc((size_t)N * HID * 2);
  float* a_src    = (float*)alloc((size_t)N * 4 * 4);
  float* a_dst    = (float*)alloc((size_t)N * 4 * 4);
  int*   cnt      = (int*)alloc((size_t)N * 4);
  int*   row_ptr  = (int*)alloc((size_t)(N + 1) * 4);
  int*   erank    = (int*)alloc((size_t)E * 4);
  int*   blk_tot  = (int*)alloc(256 * 4);
  int*   csr_src  = (int*)alloc((size_t)E * 4);
  float* G        = (float*)alloc(HID * HID * 4);
  float* Hm       = (float*)alloc(HID * HID * 4);
  float* bias2    = (float*)alloc(HID * 4);
  float* sigma_inv= (float*)alloc(256);
  u16*   Wg16     = (u16*)alloc(HID * HID * 2);
  u16*   W1t      = (u16*)alloc(HID * HID * 2);
  u16*   W2t      = (u16*)alloc(HID * HID * 2);
  u16*   Wot      = (u16*)alloc(3 * HID * HID * 2);

  const int ntXP = (N + 127) / 128;
  const int ntiles64 = (N + 63) / 64;
  int NHc = 1024 - 64 - ntXP;
  if (NHc < 128) NHc = 128;

  // K_prep: gat_w transpose + cnt zeroing (one dispatch, no runtime fill)
  K_prep<<<HID + NZB, HID, 0, stream>>>(gat_w, Wg16, cnt, N);

  // K_front: xp_mfma | build_G | hist_rank (all co-resident, full overlap)
  K_front<<<ntXP + 64 + NHc, 256, 0, stream>>>(
      x, Wg16, att_src, att_dst, xp, a_src, a_dst, N, ntXP, NHc,
      pc_w, G, ei, E, N, cnt, erank);

  // K_scan: scan_local | mat_sq
  K_scan<<<NB + 16, 1024, 0, stream>>>(cnt, row_ptr, blk_tot, N, NB, G, Hm);

  // K_apply: scan_apply | power_iter
  K_apply<<<NB + 1, 256, 0, stream>>>(row_ptr, blk_tot, N, NB, Hm, sigma_inv);

  // K_fill: fill_rank | prep_all
  K_fill<<<1024 + HID + 5, 256, 0, stream>>>(
      ei, E, N, row_ptr, erank, csr_src,
      pc_w, sigma_inv, mgf_w, mgf_b, sym_w, sym_b, out_w,
      W1t, W2t, Wot, bias2);

  // GAT aggregation (4 dsts per 256-thread block -> 32 waves/CU)
  gat_aggregate<<<(N + 3) / 4, 256, 0, stream>>>(xp, a_src, a_dst, row_ptr, csr_src,
                                                 gat_b, h_gat, N);

  // fused tail
  tail_fused<<<ntiles64, 256, 0, stream>>>(h_gat,
      W1t, pc_b, pc_g, pc_bb,
      W2t, bias2, sym_g, sym_bb,
      Wot, out_b, norm_g, norm_b,
      (float*)d_out, N);
}

// Round 19
// 163.435 us; speedup vs baseline: 1.0599x; 1.0599x over previous
//
#include <hip/hip_runtime.h>
#include <cstddef>

#define HID 128
#define NEG_SLOPE 0.2f
#define LN_EPS 1e-5f

typedef float floatx4 __attribute__((ext_vector_type(4)));
typedef short bf16x8 __attribute__((ext_vector_type(8)));
typedef int intx4 __attribute__((ext_vector_type(4)));
typedef unsigned short u16;
typedef unsigned int u32;

#define MFMA(a, b, c) __builtin_amdgcn_mfma_f32_16x16x32_bf16((a), (b), (c), 0, 0, 0)

__device__ __forceinline__ u16 f2bf(float f) {
  union { float f; unsigned u; } v; v.f = f;
  unsigned r = v.u + 0x7FFF + ((v.u >> 16) & 1);
  return (u16)(r >> 16);
}
__device__ __forceinline__ float bf2f(u16 s) {
  union { unsigned u; float f; } v; v.u = ((unsigned)s) << 16;
  return v.f;
}

// ---------------------------------------------------------------------------
// K_prep: fused { gat_w transpose->bf16 | cnt zeroing }
// ---------------------------------------------------------------------------
__global__ void K_prep(const float* __restrict__ W, u16* __restrict__ Wg16,
                       int* __restrict__ cnt, int N) {
  const int b = blockIdx.x;
  if (b < HID) {
    const int j = b, k = threadIdx.x;
    Wg16[j*HID + k] = f2bf(W[k*HID + j]);
  } else {
    int i = (b - HID) * 128 + threadIdx.x;
    if (i < N) cnt[i] = 0;
  }
}

// ---------------------------------------------------------------------------
// K_front: fused { xp_mfma | build_G | hist_rank }; all blocks co-resident
// (4 blocks/CU * 256 CU = 1024 at 34.8KB LDS/block) => full overlap.
// ---------------------------------------------------------------------------
__global__ __launch_bounds__(256) void K_front(
    const float* __restrict__ x, const u16* __restrict__ Wg16,
    const float* __restrict__ att_src, const float* __restrict__ att_dst,
    u16* __restrict__ xp, float* __restrict__ a_src, float* __restrict__ a_dst,
    int nrows, int ntXP, int NHc,
    const float* __restrict__ pc_w, float* __restrict__ G,
    const int* __restrict__ ei, int E, int N,
    int* __restrict__ cnt, int* __restrict__ rank)
{
  __shared__ u16 Wt[128 * 136];
  const int b = blockIdx.x;
  const int tid = threadIdx.x;

  if (b < ntXP) {
    // ---------------- xp_mfma ----------------
    {
      #pragma unroll
      for (int i = 0; i < 8; ++i) {
        int idx = tid + i*256;
        bf16x8 w = *(const bf16x8*)(Wg16 + (size_t)idx*8);
        *(bf16x8*)&Wt[(idx >> 4)*136 + (idx & 15)*8] = w;
      }
    }
    __syncthreads();
    const int lane = tid & 63, wave = tid >> 6;
    const int lr = lane & 15, lg = lane >> 4;
    const int rowbase = b*128 + wave*32;

    bf16x8 a[2][4];
    #pragma unroll
    for (int rf = 0; rf < 2; ++rf) {
      int row = min(rowbase + rf*16 + lr, nrows-1);
      const float* p = x + (size_t)row*HID + lg*8;
      #pragma unroll
      for (int kc = 0; kc < 4; ++kc) {
        float4 q0 = *(const float4*)(p + kc*32);
        float4 q1 = *(const float4*)(p + kc*32 + 4);
        union { bf16x8 v; u16 s[8]; } u;
        u.s[0]=f2bf(q0.x); u.s[1]=f2bf(q0.y); u.s[2]=f2bf(q0.z); u.s[3]=f2bf(q0.w);
        u.s[4]=f2bf(q1.x); u.s[5]=f2bf(q1.y); u.s[6]=f2bf(q1.z); u.s[7]=f2bf(q1.w);
        a[rf][kc] = u.v;
      }
    }
    floatx4 acc[2][8];
    #pragma unroll
    for (int rf = 0; rf < 2; ++rf)
      #pragma unroll
      for (int cf = 0; cf < 8; ++cf) acc[rf][cf] = (floatx4){0,0,0,0};
    #pragma unroll
    for (int kc = 0; kc < 4; ++kc)
      #pragma unroll
      for (int cf = 0; cf < 8; ++cf) {
        bf16x8 bb = *(const bf16x8*)&Wt[(cf*16+lr)*136 + kc*32 + lg*8];
        acc[0][cf] = MFMA(a[0][kc], bb, acc[0][cf]);
        acc[1][cf] = MFMA(a[1][kc], bb, acc[1][cf]);
      }
    float asv[8], adv[8];
    #pragma unroll
    for (int cf = 0; cf < 8; ++cf) {
      asv[cf] = att_src[cf*16 + lr];
      adv[cf] = att_dst[cf*16 + lr];
    }
    #pragma unroll
    for (int rf = 0; rf < 2; ++rf) {
      #pragma unroll
      for (int j = 0; j < 4; ++j) {
        int row = rowbase + rf*16 + lg*4 + j;
        if (row < nrows) {
          #pragma unroll
          for (int cf = 0; cf < 8; ++cf)
            xp[(size_t)row*HID + cf*16 + lr] = f2bf(acc[rf][cf][j]);
        }
        #pragma unroll
        for (int h = 0; h < 4; ++h) {
          float ps = acc[rf][2*h][j]*asv[2*h] + acc[rf][2*h+1][j]*asv[2*h+1];
          float pd = acc[rf][2*h][j]*adv[2*h] + acc[rf][2*h+1][j]*adv[2*h+1];
          #pragma unroll
          for (int m = 1; m < 16; m <<= 1) { ps += __shfl_xor(ps, m); pd += __shfl_xor(pd, m); }
          if (lr == 0 && row < nrows) {
            a_src[(size_t)row*4 + h] = ps;
            a_dst[(size_t)row*4 + h] = pd;
          }
        }
      }
    }
  } else if (b < ntXP + 64) {
    // ---------------- build_G (2 rows/block) ----------------
    int i = (b - ntXP)*2 + (tid >> 7);
    int j = tid & 127;
    float s = 0.f;
    for (int k = 0; k < HID; ++k) s = fmaf(pc_w[k*HID + i], pc_w[k*HID + j], s);
    G[i*HID + j] = s;
  } else {
    // ---------------- hist_rank (grid-stride) ----------------
    const int vb = b - (ntXP + 64);
    const int E4 = E >> 2;
    const intx4* dst4 = (const intx4*)(ei + (size_t)E);
    intx4* rank4 = (intx4*)rank;
    const int stride = NHc * 256;
    for (int i4 = vb*256 + tid; i4 < E4; i4 += stride) {
      intx4 d4 = __builtin_nontemporal_load(&dst4[i4]);
      intx4 r;
      r.x = ((unsigned)d4.x < (unsigned)N) ? atomicAdd(&cnt[d4.x], 1) : 0;
      r.y = ((unsigned)d4.y < (unsigned)N) ? atomicAdd(&cnt[d4.y], 1) : 0;
      r.z = ((unsigned)d4.z < (unsigned)N) ? atomicAdd(&cnt[d4.z], 1) : 0;
      r.w = ((unsigned)d4.w < (unsigned)N) ? atomicAdd(&cnt[d4.w], 1) : 0;
      rank4[i4] = r;
    }
    if (vb == 0 && tid < (E & 3)) {
      int idx = (E4 << 2) + tid;
      int d = ei[(size_t)E + idx];
      rank[idx] = ((unsigned)d < (unsigned)N) ? atomicAdd(&cnt[d], 1) : 0;
    }
  }
}

// ---------------------------------------------------------------------------
// K_scan: fused { scan_local | mat_sq }  (1024 threads)
// ---------------------------------------------------------------------------
__global__ __launch_bounds__(1024) void K_scan(
    const int* __restrict__ cnt, int* __restrict__ row_ptr,
    int* __restrict__ blk_tot, int N, int NB,
    const float* __restrict__ G, float* __restrict__ Hm)
{
  __shared__ int sd[1024];
  const int b = blockIdx.x;
  const int tid = threadIdx.x;
  if (b < NB) {
    int i = b * 1024 + tid;
    int v = (i < N) ? cnt[i] : 0;
    sd[tid] = v;
    __syncthreads();
    for (int off = 1; off < 1024; off <<= 1) {
      int t = (tid >= off) ? sd[tid - off] : 0;
      __syncthreads();
      sd[tid] += t;
      __syncthreads();
    }
    if (i < N) row_ptr[i] = sd[tid] - v;
    if (tid == 1023) blk_tot[b] = sd[1023];
  } else {
    int i = (b - NB)*8 + (tid >> 7);
    int j = tid & 127;
    float s = 0.f;
    for (int k = 0; k < HID; ++k) s = fmaf(G[i*HID + k], G[k*HID + j], s);
    Hm[i*HID + j] = s;
  }
}

// ---------------------------------------------------------------------------
// K_apply: fused { scan_apply | power_iter }  (256 threads)
// ---------------------------------------------------------------------------
__global__ __launch_bounds__(256) void K_apply(
    int* __restrict__ row_ptr, const int* __restrict__ blk_tot, int N, int NB,
    const float* __restrict__ H, float* __restrict__ out_inv_sigma)
{
  __shared__ __align__(16) float Hl[128 * 132];
  __shared__ __align__(16) float v[132];
  __shared__ float ybuf[256];
  __shared__ float red[8];
  __shared__ int s_off;
  const int b = blockIdx.x;
  const int tid = threadIdx.x;

  if (b < NB) {
    if (tid < 64) {
      int carry = 0;
      for (int base = 0; base < NB; base += 64) {
        int i = base + tid;
        int vv = (i < NB) ? blk_tot[i] : 0;
        int inc = vv;
        #pragma unroll
        for (int m = 1; m < 64; m <<= 1) {
          int t = __shfl_up(inc, m);
          if (tid >= m) inc += t;
        }
        if (i == b) s_off = carry + inc - vv;
        int tot = __shfl(inc, 63);
        carry += tot;
      }
      if (b == 0 && tid == 0) row_ptr[N] = carry;
    }
    __syncthreads();
    int lim = min(N, (b + 1) * 1024);
    for (int i = b * 1024 + tid; i < lim; i += 256) row_ptr[i] += s_off;
  } else {
    {
      const float4* H4 = (const float4*)H;
      float4* Hl4 = (float4*)Hl;
      #pragma unroll
      for (int idx = tid; idx < 128*32; idx += 256) {
        int r = idx >> 5, c = idx & 31;
        Hl4[r*33 + c] = H4[idx];
      }
    }
    if (tid < 128) v[tid] = 1.0f + 0.001f * (float)tid;
    __syncthreads();
    const int j = tid & 127, half = tid >> 7;
    float rho = 0.f;
    for (int it = 0; it < 20; ++it) {
      const float4* hrow = (const float4*)(Hl + j*132 + half*64);
      const float4* vrow = (const float4*)(v) + half*16;
      float y = 0.f;
      #pragma unroll
      for (int q = 0; q < 16; ++q) {
        float4 hq = hrow[q];
        float4 vq = vrow[q];
        y += hq.x*vq.x + hq.y*vq.y + hq.z*vq.z + hq.w*vq.w;
      }
      ybuf[tid] = y;
      __syncthreads();
      float yj = 0.f, vy = 0.f, yy = 0.f;
      if (tid < 128) {
        yj = ybuf[tid] + ybuf[tid + 128];
        vy = v[tid] * yj;
        yy = yj * yj;
      }
      #pragma unroll
      for (int m = 1; m < 64; m <<= 1) { vy += __shfl_xor(vy, m); yy += __shfl_xor(yy, m); }
      if ((tid & 63) == 0) { red[tid>>6] = vy; red[4 + (tid>>6)] = yy; }
      __syncthreads();
      float vyT = red[0] + red[1] + red[2] + red[3];
      float yyT = red[4] + red[5] + red[6] + red[7];
      rho = vyT;
      if (tid < 128) v[tid] = yj * rsqrtf(yyT);
      __syncthreads();
    }
    if (tid == 0) out_inv_sigma[0] = 1.0f / sqrtf(sqrtf(rho));
  }
}

// ---------------------------------------------------------------------------
// K_fill: fused { fill_rank | prep_all }
// ---------------------------------------------------------------------------
__global__ __launch_bounds__(256) void K_fill(
    const int* __restrict__ ei, int E, int N,
    const int* __restrict__ row_ptr, const int* __restrict__ rank,
    int* __restrict__ csr_src,
    const float* __restrict__ pc_w, const float* __restrict__ sigma_inv,
    const float* __restrict__ mgf_w, const float* __restrict__ mgf_b,
    const float* __restrict__ sym_w, const float* __restrict__ sym_b,
    const float* __restrict__ out_w,
    u16* __restrict__ W1t, u16* __restrict__ W2t,
    u16* __restrict__ Wot, float* __restrict__ bias2)
{
  const int b = blockIdx.x;
  const int tid = threadIdx.x;
  if (b < 1024) {
    const int E4 = E >> 2;
    const intx4* src4v = (const intx4*)ei;
    const intx4* dst4v = (const intx4*)(ei + (size_t)E);
    const intx4* rank4 = (const intx4*)rank;
    const int stride = 1024 * 256;
    for (int i4 = b*256 + tid; i4 < E4; i4 += stride) {
      intx4 d4 = __builtin_nontemporal_load(&dst4v[i4]);
      intx4 s4 = __builtin_nontemporal_load(&src4v[i4]);
      intx4 r4 = __builtin_nontemporal_load(&rank4[i4]);
      if ((unsigned)d4.x < (unsigned)N && (unsigned)s4.x < (unsigned)N)
        csr_src[row_ptr[d4.x] + r4.x] = s4.x;
      if ((unsigned)d4.y < (unsigned)N && (unsigned)s4.y < (unsigned)N)
        csr_src[row_ptr[d4.y] + r4.y] = s4.y;
      if ((unsigned)d4.z < (unsigned)N && (unsigned)s4.z < (unsigned)N)
        csr_src[row_ptr[d4.z] + r4.z] = s4.z;
      if ((unsigned)d4.w < (unsigned)N && (unsigned)s4.w < (unsigned)N)
        csr_src[row_ptr[d4.w] + r4.w] = s4.w;
    }
    if (b == 0 && tid < (E & 3)) {
      int idx = ((E >> 2) << 2) + tid;
      int d = ei[(size_t)E + idx];
      int s = ei[idx];
      if ((unsigned)d < (unsigned)N && (unsigned)s < (unsigned)N)
        csr_src[row_ptr[d] + rank[idx]] = s;
    }
  } else if (tid < 128) {
    const int bb = b - 1024;
    const int j = tid;
    if (bb < HID) {
      float s = 0.f;
      for (int m = 0; m < HID; ++m) s = fmaf(mgf_w[bb*HID + m], sym_w[m*HID + j], s);
      W2t[j*HID + bb] = f2bf(s);
    } else if (bb == HID) {
      float s = sym_b[j];
      for (int m = 0; m < HID; ++m) s = fmaf(mgf_b[m], sym_w[m*HID + j], s);
      bias2[j] = s;
    } else if (bb == HID + 1) {
      float sc = sigma_inv[0];
      for (int k = 0; k < HID; ++k) W1t[j*HID + k] = f2bf(pc_w[k*HID + j] * sc);
    } else {
      int p = bb - (HID + 2);
      for (int k = 0; k < HID; ++k)
        Wot[p*HID*HID + j*HID + k] = f2bf(out_w[(size_t)(p*HID + k)*HID + j]);
    }
  }
}

// ---------------------------------------------------------------------------
// GAT aggregation: one 64-lane wave per dst, 2 channels/lane, inline weights.
// (64-thread blocks — empirically fastest; 4-wave repack regressed (r18).)
// ---------------------------------------------------------------------------
__global__ __launch_bounds__(64) void gat_aggregate(
    const u16* __restrict__ xp, const float* __restrict__ a_src,
    const float* __restrict__ a_dst, const int* __restrict__ row_ptr,
    const int* __restrict__ csr_src, const float* __restrict__ gat_b,
    u16* __restrict__ h_gat, int N)
{
  const int d = blockIdx.x;
  const int lane = threadIdx.x;
  const int hh = lane >> 4;
  const int c0 = lane * 2;
  const int beg = row_ptr[d], end = row_ptr[d+1];

  const float ad = a_dst[(size_t)d*4 + hh];
  float e0 = a_src[(size_t)d*4 + hh] + ad;
  e0 = (e0 > 0.f) ? e0 : NEG_SLOPE * e0;
  float w0 = __expf(e0);
  u32 xv = *(const u32*)(xp + (size_t)d*HID + c0);
  float acc0 = w0 * bf2f((u16)(xv & 0xFFFF));
  float acc1 = w0 * bf2f((u16)(xv >> 16));
  float den = w0;

  int i = beg;
  for (; i + 4 <= end; i += 4) {
    int s0 = csr_src[i+0], s1 = csr_src[i+1], s2 = csr_src[i+2], s3 = csr_src[i+3];
    float eA = a_src[(size_t)s0*4 + hh] + ad;
    float eB = a_src[(size_t)s1*4 + hh] + ad;
    float eC = a_src[(size_t)s2*4 + hh] + ad;
    float eD = a_src[(size_t)s3*4 + hh] + ad;
    eA = (eA > 0.f) ? eA : NEG_SLOPE * eA;
    eB = (eB > 0.f) ? eB : NEG_SLOPE * eB;
    eC = (eC > 0.f) ? eC : NEG_SLOPE * eC;
    eD = (eD > 0.f) ? eD : NEG_SLOPE * eD;
    float wA = __expf(eA), wB = __expf(eB), wC = __expf(eC), wD = __expf(eD);
    u32 xA = *(const u32*)(xp + (size_t)s0*HID + c0);
    u32 xB = *(const u32*)(xp + (size_t)s1*HID + c0);
    u32 xC = *(const u32*)(xp + (size_t)s2*HID + c0);
    u32 xD = *(const u32*)(xp + (size_t)s3*HID + c0);
    acc0 = fmaf(wA, bf2f((u16)(xA & 0xFFFF)), acc0);
    acc1 = fmaf(wA, bf2f((u16)(xA >> 16)),    acc1);
    acc0 = fmaf(wB, bf2f((u16)(xB & 0xFFFF)), acc0);
    acc1 = fmaf(wB, bf2f((u16)(xB >> 16)),    acc1);
    acc0 = fmaf(wC, bf2f((u16)(xC & 0xFFFF)), acc0);
    acc1 = fmaf(wC, bf2f((u16)(xC >> 16)),    acc1);
    acc0 = fmaf(wD, bf2f((u16)(xD & 0xFFFF)), acc0);
    acc1 = fmaf(wD, bf2f((u16)(xD >> 16)),    acc1);
    den += (wA + wB) + (wC + wD);
  }
  for (; i < end; ++i) {
    int s = csr_src[i];
    float e = a_src[(size_t)s*4 + hh] + ad;
    e = (e > 0.f) ? e : NEG_SLOPE * e;
    float w = __expf(e);
    u32 xw = *(const u32*)(xp + (size_t)s*HID + c0);
    acc0 = fmaf(w, bf2f((u16)(xw & 0xFFFF)), acc0);
    acc1 = fmaf(w, bf2f((u16)(xw >> 16)),    acc1);
    den += w;
  }
  float inv = 1.0f / (den + 1e-16f);
  float o0 = acc0 * inv + gat_b[c0];
  float o1 = acc1 * inv + gat_b[c0 + 1];
  u32 pack = (u32)f2bf(o0) | ((u32)f2bf(o1) << 16);
  *(u32*)(h_gat + (size_t)d*HID + c0) = pack;
}

// ---------------------------------------------------------------------------
// tail_fused: 256 threads, 64 rows/block. 5 GEMM passes over ONE LDS weight
// buffer (restaged with barriers, issue-early/write-late). T is wave-local.
// ---------------------------------------------------------------------------
__global__ __launch_bounds__(256) void tail_fused(
    const u16* __restrict__ A,
    const u16* __restrict__ W1t, const float* __restrict__ b1,
    const float* __restrict__ g1, const float* __restrict__ bb1,
    const u16* __restrict__ W2t, const float* __restrict__ b2,
    const float* __restrict__ g2, const float* __restrict__ bb2,
    const u16* __restrict__ Wot,
    const float* __restrict__ out_b,
    const float* __restrict__ norm_g, const float* __restrict__ norm_b,
    float* __restrict__ Cout, int nrows)
{
  __shared__ u16 Wbuf[128 * 136];
  __shared__ u16 T[64 * 136];
  const int tid = threadIdx.x;
  const int lane = tid & 63, wave = tid >> 6;
  const int lr = lane & 15, lg = lane >> 4;
  const int rowbase = blockIdx.x * 64;

  int arow = min(rowbase + wave*16 + lr, nrows-1);
  const u16* ap = A + (size_t)arow*HID + lg*8;
  bf16x8 a0 = *(const bf16x8*)(ap);
  bf16x8 a1 = *(const bf16x8*)(ap + 32);
  bf16x8 a2 = *(const bf16x8*)(ap + 64);
  bf16x8 a3 = *(const bf16x8*)(ap + 96);

  bf16x8 st[8];
  auto loadW = [&](const u16* Wsrc) {
    #pragma unroll
    for (int i = 0; i < 8; ++i)
      st[i] = *(const bf16x8*)(Wsrc + (size_t)(tid + i*256) * 8);
  };
  auto writeW = [&]() {
    #pragma unroll
    for (int i = 0; i < 8; ++i) {
      int c = tid + i*256;
      *(bf16x8*)&Wbuf[(c >> 4)*136 + (c & 15)*8] = st[i];
    }
  };
  auto gemmW = [&](floatx4* acc, bf16x8 x0, bf16x8 x1, bf16x8 x2, bf16x8 x3) {
    #pragma unroll
    for (int cf = 0; cf < 8; ++cf) {
      const u16* wb = &Wbuf[(cf*16+lr)*136 + lg*8];
      acc[cf] = MFMA(x0, *(const bf16x8*)(wb),       acc[cf]);
      acc[cf] = MFMA(x1, *(const bf16x8*)(wb + 32),  acc[cf]);
      acc[cf] = MFMA(x2, *(const bf16x8*)(wb + 64),  acc[cf]);
      acc[cf] = MFMA(x3, *(const bf16x8*)(wb + 96),  acc[cf]);
    }
  };
  auto epiT = [&](floatx4* acc, const float* bias, const float* lng, const float* lnb) {
    #pragma unroll
    for (int j = 0; j < 4; ++j) {
      float vv[8]; float s1 = 0.f, s2 = 0.f;
      #pragma unroll
      for (int cf = 0; cf < 8; ++cf) {
        vv[cf] = acc[cf][j] + bias[cf*16 + lr];
        s1 += vv[cf]; s2 += vv[cf]*vv[cf];
      }
      #pragma unroll
      for (int m = 1; m < 16; m <<= 1) { s1 += __shfl_xor(s1, m); s2 += __shfl_xor(s2, m); }
      float mean = s1 * (1.0f/128.0f);
      float var  = s2 * (1.0f/128.0f) - mean*mean;
      float rstd = rsqrtf(var + LN_EPS);
      int lrow = wave*16 + lg*4 + j;
      #pragma unroll
      for (int cf = 0; cf < 8; ++cf) {
        float o = fmaxf((vv[cf]-mean)*rstd*lng[cf*16+lr] + lnb[cf*16+lr], 0.f);
        T[lrow*136 + cf*16 + lr] = f2bf(o);
      }
    }
  };

  floatx4 accO[8];
  #pragma unroll
  for (int cf = 0; cf < 8; ++cf) accO[cf] = (floatx4){0,0,0,0};

  loadW(W1t);
  writeW(); __syncthreads();
  loadW(Wot + (size_t)1*HID*HID);
  {
    floatx4 accT[8];
    #pragma unroll
    for (int cf = 0; cf < 8; ++cf) accT[cf] = (floatx4){0,0,0,0};
    gemmW(accT, a0, a1, a2, a3);
    epiT(accT, b1, g1, bb1);
  }
  __syncthreads();
  writeW(); __syncthreads();
  loadW(W2t);
  {
    const u16* tp = &T[(wave*16 + lr)*136 + lg*8];
    bf16x8 t0 = *(const bf16x8*)(tp);
    bf16x8 t1 = *(const bf16x8*)(tp + 32);
    bf16x8 t2 = *(const bf16x8*)(tp + 64);
    bf16x8 t3 = *(const bf16x8*)(tp + 96);
    gemmW(accO, t0, t1, t2, t3);
  }
  __syncthreads();
  writeW(); __syncthreads();
  loadW(Wot + (size_t)2*HID*HID);
  {
    floatx4 accT[8];
    #pragma unroll
    for (int cf = 0; cf < 8; ++cf) accT[cf] = (floatx4){0,0,0,0};
    gemmW(accT, a0, a1, a2, a3);
    epiT(accT, b2, g2, bb2);
  }
  __syncthreads();
  writeW(); __syncthreads();
  loadW(Wot);
  {
    const u16* tp = &T[(wave*16 + lr)*136 + lg*8];
    bf16x8 t0 = *(const bf16x8*)(tp);
    bf16x8 t1 = *(const bf16x8*)(tp + 32);
    bf16x8 t2 = *(const bf16x8*)(tp + 64);
    bf16x8 t3 = *(const bf16x8*)(tp + 96);
    gemmW(accO, t0, t1, t2, t3);
  }
  __syncthreads();
  writeW(); __syncthreads();
  gemmW(accO, a0, a1, a2, a3);

  #pragma unroll
  for (int j = 0; j < 4; ++j) {
    float vv[8]; float s1 = 0.f, s2 = 0.f;
    #pragma unroll
    for (int cf = 0; cf < 8; ++cf) {
      vv[cf] = accO[cf][j] + out_b[cf*16 + lr];
      s1 += vv[cf]; s2 += vv[cf]*vv[cf];
    }
    #pragma unroll
    for (int m = 1; m < 16; m <<= 1) { s1 += __shfl_xor(s1, m); s2 += __shfl_xor(s2, m); }
    float mean = s1 * (1.0f/128.0f);
    float var  = s2 * (1.0f/128.0f) - mean*mean;
    float rstd = rsqrtf(var + LN_EPS);
    int row = rowbase + wave*16 + lg*4 + j;
    if (row < nrows) {
      #pragma unroll
      for (int cf = 0; cf < 8; ++cf)
        Cout[(size_t)row*HID + cf*16 + lr] = (vv[cf]-mean)*rstd*norm_g[cf*16+lr] + norm_b[cf*16+lr];
    }
  }
}

// ---------------------------------------------------------------------------
// launch
// ---------------------------------------------------------------------------
extern "C" void kernel_launch(void* const* d_in, const int* in_sizes, int n_in,
                              void* d_out, int out_size, void* d_ws, size_t ws_size,
                              hipStream_t stream) {
  const float* x       = (const float*)d_in[0];
  const float* gat_w   = (const float*)d_in[2];
  const float* att_src = (const float*)d_in[3];
  const float* att_dst = (const float*)d_in[4];
  const float* gat_b   = (const float*)d_in[5];
  const float* pc_w    = (const float*)d_in[6];
  const float* pc_b    = (const float*)d_in[7];
  const float* pc_g    = (const float*)d_in[8];
  const float* pc_bb   = (const float*)d_in[9];
  const float* mgf_w   = (const float*)d_in[10];
  const float* mgf_b   = (const float*)d_in[11];
  const float* sym_w   = (const float*)d_in[12];
  const float* sym_b   = (const float*)d_in[13];
  const float* sym_g   = (const float*)d_in[14];
  const float* sym_bb  = (const float*)d_in[15];
  const float* out_w   = (const float*)d_in[16];
  const float* out_b   = (const float*)d_in[17];
  const float* norm_g  = (const float*)d_in[18];
  const float* norm_b  = (const float*)d_in[19];
  const int*   ei      = (const int*)d_in[20];

  const int N = in_sizes[0] / HID;
  const int E = in_sizes[1];
  const int NB = (N + 1023) / 1024;
  const int NZB = (N + 127) / 128;

  char* ws = (char*)d_ws;
  size_t off = 0;
  auto alloc = [&](size_t bytes) -> void* {
    void* p = ws + off;
    off += (bytes + 255) & ~(size_t)255;
    return p;
  };
  u16*   xp       = (u16*)alloc((size_t)N * HID * 2);
  u16*   h_gat    = (u16*)alloc((size_t)N * HID * 2);
  float* a_src    = (float*)alloc((size_t)N * 4 * 4);
  float* a_dst    = (float*)alloc((size_t)N * 4 * 4);
  int*   cnt      = (int*)alloc((size_t)N * 4);
  int*   row_ptr  = (int*)alloc((size_t)(N + 1) * 4);
  int*   erank    = (int*)alloc((size_t)E * 4);
  int*   blk_tot  = (int*)alloc(256 * 4);
  int*   csr_src  = (int*)alloc((size_t)E * 4);
  float* G        = (float*)alloc(HID * HID * 4);
  float* Hm       = (float*)alloc(HID * HID * 4);
  float* bias2    = (float*)alloc(HID * 4);
  float* sigma_inv= (float*)alloc(256);
  u16*   Wg16     = (u16*)alloc(HID * HID * 2);
  u16*   W1t      = (u16*)alloc(HID * HID * 2);
  u16*   W2t      = (u16*)alloc(HID * HID * 2);
  u16*   Wot      = (u16*)alloc(3 * HID * HID * 2);

  const int ntXP = (N + 127) / 128;
  const int ntiles64 = (N + 63) / 64;
  int NHc = 1024 - 64 - ntXP;
  if (NHc < 128) NHc = 128;

  // K_prep: gat_w transpose + cnt zeroing
  K_prep<<<HID + NZB, HID, 0, stream>>>(gat_w, Wg16, cnt, N);

  // K_front: xp_mfma | build_G | hist_rank (all co-resident, full overlap)
  K_front<<<ntXP + 64 + NHc, 256, 0, stream>>>(
      x, Wg16, att_src, att_dst, xp, a_src, a_dst, N, ntXP, NHc,
      pc_w, G, ei, E, N, cnt, erank);

  // K_scan: scan_local | mat_sq
  K_scan<<<NB + 16, 1024, 0, stream>>>(cnt, row_ptr, blk_tot, N, NB, G, Hm);

  // K_apply: scan_apply | power_iter
  K_apply<<<NB + 1, 256, 0, stream>>>(row_ptr, blk_tot, N, NB, Hm, sigma_inv);

  // K_fill: fill_rank | prep_all
  K_fill<<<1024 + HID + 5, 256, 0, stream>>>(
      ei, E, N, row_ptr, erank, csr_src,
      pc_w, sigma_inv, mgf_w, mgf_b, sym_w, sym_b, out_w,
      W1t, W2t, Wot, bias2);

  // GAT aggregation (one 64-thread block per dst)
  gat_aggregate<<<N, 64, 0, stream>>>(xp, a_src, a_dst, row_ptr, csr_src,
                                      gat_b, h_gat, N);

  // fused tail
  tail_fused<<<ntiles64, 256, 0, stream>>>(h_gat,
      W1t, pc_b, pc_g, pc_bb,
      W2t, bias2, sym_g, sym_bb,
      Wot, out_b, norm_g, norm_b,
      (float*)d_out, N);
}